// Round 7
// baseline (172.546 us; speedup 1.0000x reference)
//
#include <hip/hip_runtime.h>

typedef __attribute__((ext_vector_type(8))) short short8;
typedef __attribute__((ext_vector_type(8))) unsigned short ushort8;
typedef __attribute__((ext_vector_type(4))) float f32x4;

#define B_   32
#define L_   8192
#define IN_  512
#define HID_ 512
#define D3_  128

static __device__ __forceinline__ short f2bf(float f) {
    return __builtin_bit_cast(short, (__bf16)f);
}
static __device__ __forceinline__ unsigned short f2bfu(float f) {
    return __builtin_bit_cast(unsigned short, (__bf16)f);
}

// async global->LDS, 16B per lane (dest effectively base + lane*16, per R6-validated idiom)
static __device__ __forceinline__ void gload_lds16(const void* g, void* l) {
    __builtin_amdgcn_global_load_lds(
        (const __attribute__((address_space(1))) unsigned int*)g,
        (__attribute__((address_space(3))) unsigned int*)l, 16, 0, 0);
}

// ---- prep: Wh (f32, D3 x HID) -> bf16 bits in ws ----
__global__ void prep_whb(const float* __restrict__ wh, unsigned short* __restrict__ whb) {
    int i = (blockIdx.x * 256 + threadIdx.x) * 4;   // 65536 elems / 4
    float4 f = *(const float4*)(wh + i);
    whb[i + 0] = f2bfu(f.x);
    whb[i + 1] = f2bfu(f.y);
    whb[i + 2] = f2bfu(f.z);
    whb[i + 3] = f2bfu(f.w);
}

// ---- prep: qpb[b][d] = inputs[b] . Wi[d] + bi[d] + bh[d]  (fp32) ----
__global__ void prep_qpb(const float* __restrict__ inputs, const float* __restrict__ Wi,
                         const float* __restrict__ bi, const float* __restrict__ bh,
                         float* __restrict__ qpb) {
    int b = blockIdx.x;
    int d = threadIdx.x;                 // 128 threads
    float acc = bi[d] + bh[d];
    const float* xr = inputs + b * IN_;
    const float* wr = Wi + d * IN_;
    #pragma unroll 4
    for (int i = 0; i < IN_; i += 4) {
        float4 x = *(const float4*)(xr + i);
        float4 w = *(const float4*)(wr + i);
        acc += x.x * w.x + x.y * w.y + x.z * w.z + x.w * w.w;
    }
    qpb[b * D3_ + d] = acc;
}

// ---- main ----
// R6 limiter: context in-flight was only ~16 KB/CU (pipeline depth floor).
// R7: Wh is NOT kept fully LDS-resident. B streams in 64-k windows (16 KiB)
// from the L2-hot bf16 copy in ws through a 2-slot ring; context staging
// gets 128 KiB = 8 chunks/wave (4 windows deep). Per window (2 K-steps):
//   barrA -> stage B(W+1) + ctx(W+3) (always 6 issues, tail = clamped
//   dummy re-stages of identical data) -> s_waitcnt vmcnt(10) (leaves
//   B(W+1)+ctx(W+2..W+3) = 10 newest outstanding; B(W) is 11th-newest ->
//   guaranteed landed; ~10 KB/wave = 80 KB/CU in flight) -> barrB
//   (cross-wave B visibility) -> 2 K-steps of MFMA.
// barrA protects the B-slot being overwritten from waves still computing
// the previous window. ctx chunks are wave-private: no barrier needed.
__global__ __launch_bounds__(512) void attn_main(
    const float* __restrict__ ctx, const unsigned short* __restrict__ whb,
    const float* __restrict__ qpb, const float* __restrict__ V,
    float* __restrict__ out)
{
    __shared__ unsigned short bwin[2][8192];     // 32 KiB: 2 x (128 cols x 64 k bf16)
    __shared__ float ctxs[8][8][512];            // 128 KiB: [wave][slot][16 rows x 32 f32]

    const int tid  = threadIdx.x;
    const int lane = tid & 63;
    const int w    = tid >> 6;           // wave 0..7, owns 16 rows
    const int cb   = lane & 15;          // A-row / C-col index
    const int g    = lane >> 4;          // k-group 0..3

    // DMA lane constants (shared by ctx and B staging)
    const int ri  = lane >> 3;           // row-in-8 / col-in-8
    const int sl  = lane & 7;            // linear 16B slot this lane fills
    const int ssl = sl ^ ri;             // swizzled slot this lane fetches
    const float* gbase = ctx + ((size_t)blockIdx.x * 1024 + w * 16 + ri) * (size_t)HID_ + ssl * 4;
    char* lctx = (char*)&ctxs[w][0][0] + lane * 16;

    const unsigned short* bsrc = whb + (16 * w + ri) * HID_ + ssl * 8;
    char* lb = (char*)bwin + w * 2048 + lane * 16;

    // A-read: row cb of the chunk, 2x16B at k-slots (2g)^key, (2g+1)^key
    const char* actx = (char*)&ctxs[w][0][0] + (cb >> 3) * 1024 + (cb & 7) * 128;
    const int aoff0 = (((2 * g)     ^ (cb & 7)) << 4);
    const int aoff1 = (((2 * g + 1) ^ (cb & 7)) << 4);
    // B-read: col (nt*16+cb), slot (kk*4+g)^(cb&7)
    const char* bbase = (const char*)bwin + cb * 128;

    const int b = blockIdx.x >> 3;       // 1024 rows per block, 8 blocks per batch

    float vv[8], qv[8];
    #pragma unroll
    for (int nt = 0; nt < 8; ++nt) {
        vv[nt] = V[nt * 16 + cb];
        qv[nt] = qpb[b * D3_ + nt * 16 + cb];
    }

#define STAGE_CTX(CC) { \
    const int cc_ = ((CC) > 127) ? (126 | ((CC) & 1)) : (CC); \
    const float* g0_ = gbase + (size_t)(cc_ >> 4) * (128 * HID_) + (cc_ & 15) * 32; \
    char* l0_ = lctx + (cc_ & 7) * 2048; \
    gload_lds16(g0_, l0_); \
    gload_lds16(g0_ + 8 * HID_, l0_ + 1024); }

#define STAGE_B(WN) { \
    const unsigned short* b0_ = bsrc + ((WN) & 7) * 64; \
    char* l0_ = lb + ((WN) & 1) * 16384; \
    gload_lds16(b0_, l0_); \
    gload_lds16(b0_ + 8 * HID_, l0_ + 1024); }

    // prologue: B(0) + ctx windows 0..2 (chunks 0..5)
    STAGE_B(0)
    STAGE_CTX(0) STAGE_CTX(1) STAGE_CTX(2)
    STAGE_CTX(3) STAGE_CTX(4) STAGE_CTX(5)

    f32x4 acc[8];

    #pragma unroll 1
    for (int W = 0; W < 64; ++W) {       // 64 windows = 8 tiles x 8 windows
        const int wt = W & 7;
        if (wt == 0) {
            #pragma unroll
            for (int nt = 0; nt < 8; ++nt) acc[nt] = (f32x4){0.f, 0.f, 0.f, 0.f};
        }

        __builtin_amdgcn_s_barrier();                    // barrA: B-slot (W+1)&1 free
        __builtin_amdgcn_sched_barrier(0);
        STAGE_B(W + 1)
        STAGE_CTX(2 * W + 6)
        STAGE_CTX(2 * W + 7)
        asm volatile("s_waitcnt vmcnt(10)" ::: "memory"); // B(W), ctx(W..W+1) landed
        __builtin_amdgcn_sched_barrier(0);
        __builtin_amdgcn_s_barrier();                    // barrB: all waves' B(W) visible
        __builtin_amdgcn_sched_barrier(0);

        const char* bwp = bbase + (W & 1) * 16384;
        #pragma unroll
        for (int kk = 0; kk < 2; ++kk) {
            const char* ab = actx + ((2 * W + kk) & 7) * 2048;
            const f32x4 a0 = *(const f32x4*)(ab + aoff0);
            const f32x4 a1 = *(const f32x4*)(ab + aoff1);
            short8 aA;
            aA[0] = f2bf(a0[0]); aA[1] = f2bf(a0[1]); aA[2] = f2bf(a0[2]); aA[3] = f2bf(a0[3]);
            aA[4] = f2bf(a1[0]); aA[5] = f2bf(a1[1]); aA[6] = f2bf(a1[2]); aA[7] = f2bf(a1[3]);
            const int boff = (((kk * 4 + g) ^ (cb & 7)) << 4);
            #pragma unroll
            for (int nt = 0; nt < 8; ++nt) {
                const short8 bb = *(const short8*)(bwp + nt * 2048 + boff);
                acc[nt] = __builtin_amdgcn_mfma_f32_16x16x32_bf16(aA, bb, acc[nt], 0, 0, 0);
            }
        }

        if (wt == 7) {
            // epilogue for tile t = W>>3: tanh(acc + q) . V, reduce over cb lanes
            float s0 = 0.f, s1 = 0.f, s2 = 0.f, s3 = 0.f;
            #pragma unroll
            for (int nt = 0; nt < 8; ++nt) {
                const float q = qv[nt], vn = vv[nt];
                s0 += (1.f - 2.f / (__expf(2.f * (acc[nt][0] + q)) + 1.f)) * vn;
                s1 += (1.f - 2.f / (__expf(2.f * (acc[nt][1] + q)) + 1.f)) * vn;
                s2 += (1.f - 2.f / (__expf(2.f * (acc[nt][2] + q)) + 1.f)) * vn;
                s3 += (1.f - 2.f / (__expf(2.f * (acc[nt][3] + q)) + 1.f)) * vn;
            }
            #pragma unroll
            for (int m = 1; m < 16; m <<= 1) {
                s0 += __shfl_xor(s0, m, 64);
                s1 += __shfl_xor(s1, m, 64);
                s2 += __shfl_xor(s2, m, 64);
                s3 += __shfl_xor(s3, m, 64);
            }
            if (cb == 0) {
                const size_t row0 = (size_t)blockIdx.x * 1024 + (size_t)(W >> 3) * 128 + w * 16;
                const size_t off_ = row0 + (size_t)g * 4;
                *(float4*)(out + off_) = make_float4(s0, s1, s2, s3);
                *(float4*)(out + (size_t)B_ * L_ + off_) = make_float4(1.f, 1.f, 1.f, 1.f);
            }
        }
    }
#undef STAGE_CTX
#undef STAGE_B
}

extern "C" void kernel_launch(void* const* d_in, const int* in_sizes, int n_in,
                              void* d_out, int out_size, void* d_ws, size_t ws_size,
                              hipStream_t stream) {
    const float* inputs  = (const float*)d_in[0];   // (32, 512)
    const float* context = (const float*)d_in[1];   // (32, 8192, 512)
    const float* Wi      = (const float*)d_in[2];   // (128, 512)
    const float* bi      = (const float*)d_in[3];   // (128,)
    const float* Wh      = (const float*)d_in[4];   // (128, 512)
    const float* bh      = (const float*)d_in[5];   // (128,)
    const float* V       = (const float*)d_in[6];   // (128,)
    float* out = (float*)d_out;                     // [att_row 262144][att 262144]

    unsigned short* whb = (unsigned short*)d_ws;                   // 128 KiB
    float* qpb = (float*)((char*)d_ws + (size_t)D3_ * HID_ * 2);   // 16 KiB

    prep_whb<<<64, 256, 0, stream>>>(Wh, whb);
    prep_qpb<<<B_, D3_, 0, stream>>>(inputs, Wi, bi, bh, qpb);
    attn_main<<<256, 512, 0, stream>>>(context, whb, qpb, V, out);
}